// Round 3
// baseline (8972.109 us; speedup 1.0000x reference)
//
#include <hip/hip_runtime.h>
#include <hip/hip_bf16.h>
#include <stdint.h>

// Few-shot matching-network head + Conv4 backbone (MI355X, gfx950). Round 3.
//
// Defensive rewrite: rounds 1 (fp32 reads) and 2 (bf16 reads) both produced the
// exact all-zeros absmax signature (0.78515625 = max|ref|). ReLU(NaN)=0 makes a
// single NaN-poisoned early tensor collapse the whole net to exact zeros, so a
// wrong dtype guess is indistinguishable from a failed launch. This version:
//   - detects fp32-vs-bf16 on device (probe W2 halfword exponents) and branches
//     uniformly on a flag for all external loads AND the output store,
//   - uses a small workspace (3.0 MB fixed + 0.6 MB/image chunk, CH adapts to 1),
//   - uses only plain file-scope non-template kernels.

#define BB 8
#define SS 25
#define TT 75
#define CC 5
#define DD 2304
#define NSUP 200
#define NTGT 600
#define EPSF 1e-8f

__device__ __forceinline__ float load_ext(const void* p, size_t idx, int isf32) {
  if (isf32) return ((const float*)p)[idx];
  unsigned short u = ((const unsigned short*)p)[idx];
  union { unsigned int i; float f; } v;
  v.i = ((unsigned int)u) << 16;
  return v.f;
}

// ---- dtype probe: count "insane" bf16 interpretations of W2's halfwords ----
// true bf16 N(0,0.05) weights: exponent bits in ~[0x69,0x84] -> ~0 insane.
// fp32 data read as halfwords: low halves have uniform-random exponents -> ~42%
// of all halfwords insane (incl. NaN patterns). flag=1 => data is fp32.
__global__ void fsc_probe_dtype_k(const unsigned short* __restrict__ w2raw,
                                  int nelems, int* __restrict__ flag) {
  __shared__ int cnt;
  if (threadIdx.x == 0) cnt = 0;
  __syncthreads();
  int local = 0;
  for (int i = threadIdx.x; i < nelems; i += 256) {
    unsigned short u = w2raw[i];
    int ex = (u >> 7) & 0xFF;
    if (ex != 0 && (ex < 0x69 || ex > 0x84)) local++;  // huge/tiny/NaN/Inf
  }
  atomicAdd(&cnt, local);
  __syncthreads();
  if (threadIdx.x == 0) *flag = (cnt > nelems / 8) ? 1 : 0;
}

// ---- weight repack: OIHW [64][CIN][3][3] -> fp32 [CIN*9][64] ----
__global__ void fsc_repack_w_k(const void* __restrict__ W, float* __restrict__ Wr,
                               int CIN, const int* __restrict__ flag) {
  const int isf32 = *flag;
  int i = blockIdx.x * blockDim.x + threadIdx.x;
  int total = 64 * CIN * 9;
  if (i >= total) return;
  int co = i / (CIN * 9);
  int r = i - co * CIN * 9;  // ci*9 + kh*3 + kw
  Wr[r * 64 + co] = load_ext(W, i, isf32);
}

// ================= conv kernels (stride 2, SAME, ReLU, NCHW) =================
// conv1: external input [n][3][84][84] -> fp32 [n][64][42][42], pad top 0.
__global__ void fsc_conv1_k(const void* __restrict__ x, size_t base,
                            const float* __restrict__ Wr, const void* __restrict__ bias,
                            float* __restrict__ out, int N, const int* __restrict__ flag) {
  const int isf32 = *flag;
  int idx = blockIdx.x * blockDim.x + threadIdx.x;
  const int n = idx / 1764;
  const int sp = idx - n * 1764;
  if (n >= N) return;
  const int ho = sp / 42, wo = sp - ho * 42;
  float acc[64];
#pragma unroll
  for (int j = 0; j < 64; ++j) acc[j] = 0.f;
  const size_t inn = base + (size_t)n * 3 * 84 * 84;
  for (int ci = 0; ci < 3; ++ci) {
#pragma unroll
    for (int kh = 0; kh < 3; ++kh) {
      const int hi = 2 * ho + kh;
      const bool hok = hi < 84;
#pragma unroll
      for (int kw = 0; kw < 3; ++kw) {
        const int wi = 2 * wo + kw;
        const float val = (hok && wi < 84) ? load_ext(x, inn + (ci * 84 + hi) * 84 + wi, isf32) : 0.f;
        const float* wp = Wr + ((ci * 3 + kh) * 3 + kw) * 64;
#pragma unroll
        for (int j = 0; j < 64; ++j) acc[j] = fmaf(wp[j], val, acc[j]);
      }
    }
  }
  float* o = out + (size_t)n * 64 * 1764 + sp;
#pragma unroll
  for (int j = 0; j < 64; ++j) {
    float r = acc[j] + load_ext(bias, j, isf32);
    o[(size_t)j * 1764] = r > 0.f ? r : 0.f;
  }
}

// conv2: fp32 [n][64][42][42] -> fp32 [n][64][21][21], pad top 0. gridDim.y=2 (32 ch).
__global__ void fsc_conv2_k(const float* __restrict__ in, const float* __restrict__ Wr,
                            const void* __restrict__ bias, float* __restrict__ out,
                            int N, const int* __restrict__ flag) {
  const int isf32 = *flag;
  const int g = blockIdx.y;
  int idx = blockIdx.x * blockDim.x + threadIdx.x;
  const int n = idx / 441;
  const int sp = idx - n * 441;
  if (n >= N) return;
  const int ho = sp / 21, wo = sp - ho * 21;
  float acc[32];
#pragma unroll
  for (int j = 0; j < 32; ++j) acc[j] = 0.f;
  const float* inn = in + (size_t)n * 64 * 1764;
  const float* wbase = Wr + g * 32;
  for (int ci = 0; ci < 64; ++ci) {
#pragma unroll
    for (int kh = 0; kh < 3; ++kh) {
      const int hi = 2 * ho + kh;
      const bool hok = hi < 42;
#pragma unroll
      for (int kw = 0; kw < 3; ++kw) {
        const int wi = 2 * wo + kw;
        const float val = (hok && wi < 42) ? inn[(ci * 42 + hi) * 42 + wi] : 0.f;
        const float* wp = wbase + ((ci * 3 + kh) * 3 + kw) * 64;
#pragma unroll
        for (int j = 0; j < 32; ++j) acc[j] = fmaf(wp[j], val, acc[j]);
      }
    }
  }
  float* o = out + ((size_t)n * 64 + g * 32) * 441 + sp;
#pragma unroll
  for (int j = 0; j < 32; ++j) {
    float r = acc[j] + load_ext(bias, g * 32 + j, isf32);
    o[(size_t)j * 441] = r > 0.f ? r : 0.f;
  }
}

// conv3: fp32 [n][64][21][21] -> fp32 [n][64][11][11], pad 1. gridDim.y=4 (16 ch).
__global__ void fsc_conv3_k(const float* __restrict__ in, const float* __restrict__ Wr,
                            const void* __restrict__ bias, float* __restrict__ out,
                            int N, const int* __restrict__ flag) {
  const int isf32 = *flag;
  const int g = blockIdx.y;
  int idx = blockIdx.x * blockDim.x + threadIdx.x;
  const int n = idx / 121;
  const int sp = idx - n * 121;
  if (n >= N) return;
  const int ho = sp / 11, wo = sp - ho * 11;
  float acc[16];
#pragma unroll
  for (int j = 0; j < 16; ++j) acc[j] = 0.f;
  const float* inn = in + (size_t)n * 64 * 441;
  const float* wbase = Wr + g * 16;
  for (int ci = 0; ci < 64; ++ci) {
#pragma unroll
    for (int kh = 0; kh < 3; ++kh) {
      const int hi = 2 * ho + kh - 1;
      const bool hok = (hi >= 0 && hi < 21);
#pragma unroll
      for (int kw = 0; kw < 3; ++kw) {
        const int wi = 2 * wo + kw - 1;
        const float val = (hok && wi >= 0 && wi < 21) ? inn[(ci * 21 + hi) * 21 + wi] : 0.f;
        const float* wp = wbase + ((ci * 3 + kh) * 3 + kw) * 64;
#pragma unroll
        for (int j = 0; j < 16; ++j) acc[j] = fmaf(wp[j], val, acc[j]);
      }
    }
  }
  float* o = out + ((size_t)n * 64 + g * 16) * 121 + sp;
#pragma unroll
  for (int j = 0; j < 16; ++j) {
    float r = acc[j] + load_ext(bias, g * 16 + j, isf32);
    o[(size_t)j * 121] = r > 0.f ? r : 0.f;
  }
}

// conv4: fp32 [n][64][11][11] -> fp32 [n][64][6][6] (= emb rows), pad 1. gridDim.y=4.
__global__ void fsc_conv4_k(const float* __restrict__ in, const float* __restrict__ Wr,
                            const void* __restrict__ bias, float* __restrict__ out,
                            int N, const int* __restrict__ flag) {
  const int isf32 = *flag;
  const int g = blockIdx.y;
  int idx = blockIdx.x * blockDim.x + threadIdx.x;
  const int n = idx / 36;
  const int sp = idx - n * 36;
  if (n >= N) return;
  const int ho = sp / 6, wo = sp - ho * 6;
  float acc[16];
#pragma unroll
  for (int j = 0; j < 16; ++j) acc[j] = 0.f;
  const float* inn = in + (size_t)n * 64 * 121;
  const float* wbase = Wr + g * 16;
  for (int ci = 0; ci < 64; ++ci) {
#pragma unroll
    for (int kh = 0; kh < 3; ++kh) {
      const int hi = 2 * ho + kh - 1;
      const bool hok = (hi >= 0 && hi < 11);
#pragma unroll
      for (int kw = 0; kw < 3; ++kw) {
        const int wi = 2 * wo + kw - 1;
        const float val = (hok && wi >= 0 && wi < 11) ? inn[(ci * 11 + hi) * 11 + wi] : 0.f;
        const float* wp = wbase + ((ci * 3 + kh) * 3 + kw) * 64;
#pragma unroll
        for (int j = 0; j < 16; ++j) acc[j] = fmaf(wp[j], val, acc[j]);
      }
    }
  }
  float* o = out + ((size_t)n * 64 + g * 16) * 36 + sp;
#pragma unroll
  for (int j = 0; j < 16; ++j) {
    float r = acc[j] + load_ext(bias, g * 16 + j, isf32);
    o[(size_t)j * 36] = r > 0.f ? r : 0.f;
  }
}

// ---- prototypes: class segment-sum over support / CAP ----
__global__ void fsc_proto_k(const float* __restrict__ emb_s, const int* __restrict__ y,
                            float* __restrict__ protos) {
  int i = blockIdx.x * blockDim.x + threadIdx.x;  // over B*C*D
  if (i >= BB * CC * DD) return;
  int d = i % DD;
  int bc = i / DD;
  int c = bc % CC;
  int b = bc / CC;
  float sum = 0.f;
  for (int s = 0; s < SS; ++s) {
    if (y[b * SS + s] % CC == c) sum += emb_s[(size_t)(b * SS + s) * DD + d];
  }
  protos[i] = sum * 0.2f;  // / CAP (=5)
}

// ---- normalize prototypes ----
__global__ void fsc_pnorm_k(const float* __restrict__ protos, float* __restrict__ pn) {
  __shared__ float red[4];
  __shared__ float inv;
  const int bc = blockIdx.x;
  const float* p = protos + (size_t)bc * DD;
  float ss = 0.f;
  for (int d = threadIdx.x; d < DD; d += 256) { float v = p[d]; ss += v * v; }
#pragma unroll
  for (int off = 32; off > 0; off >>= 1) ss += __shfl_down(ss, off);
  if ((threadIdx.x & 63) == 0) red[threadIdx.x >> 6] = ss;
  __syncthreads();
  if (threadIdx.x == 0) {
    float nrm = sqrtf(red[0] + red[1] + red[2] + red[3]);
    nrm = nrm > EPSF ? nrm : EPSF;
    inv = 1.f / nrm;
  }
  __syncthreads();
  float sc = inv;
  for (int d = threadIdx.x; d < DD; d += 256) pn[(size_t)bc * DD + d] = p[d] * sc;
}

// ---- cosine logits for one target chunk; output dtype follows flag ----
__global__ void fsc_preds_k(const float* __restrict__ emb_t, const float* __restrict__ pn,
                            void* __restrict__ out, int tbase, const int* __restrict__ flag) {
  __shared__ float red[4][6];
  __shared__ float fin[6];
  const int isf32 = *flag;
  const int bt = tbase + blockIdx.x;
  const int b = bt / TT;
  const float* et = emb_t + (size_t)blockIdx.x * DD;
  float e[9];
#pragma unroll
  for (int k = 0; k < 9; ++k) e[k] = et[threadIdx.x + 256 * k];
  float vals[6];
  {
    float ss = 0.f;
#pragma unroll
    for (int k = 0; k < 9; ++k) ss += e[k] * e[k];
    vals[0] = ss;
  }
  const float* pb = pn + (size_t)b * CC * DD;
#pragma unroll
  for (int c = 0; c < CC; ++c) {
    float s = 0.f;
#pragma unroll
    for (int k = 0; k < 9; ++k) s += e[k] * pb[(size_t)c * DD + threadIdx.x + 256 * k];
    vals[1 + c] = s;
  }
#pragma unroll
  for (int v = 0; v < 6; ++v) {
#pragma unroll
    for (int off = 32; off > 0; off >>= 1) vals[v] += __shfl_down(vals[v], off);
  }
  if ((threadIdx.x & 63) == 0) {
#pragma unroll
    for (int v = 0; v < 6; ++v) red[threadIdx.x >> 6][v] = vals[v];
  }
  __syncthreads();
  if (threadIdx.x < 6)
    fin[threadIdx.x] = red[0][threadIdx.x] + red[1][threadIdx.x] +
                       red[2][threadIdx.x] + red[3][threadIdx.x];
  __syncthreads();
  if (threadIdx.x < CC) {
    float nt = sqrtf(fin[0]);
    nt = nt > EPSF ? nt : EPSF;
    float r = fin[1 + threadIdx.x] / nt;
    if (isf32) ((float*)out)[(size_t)bt * CC + threadIdx.x] = r;
    else ((__hip_bfloat16*)out)[(size_t)bt * CC + threadIdx.x] = __float2bfloat16(r);
  }
}

static inline int fsc_cdiv(int a, int b) { return (a + b - 1) / b; }

extern "C" void kernel_launch(void* const* d_in, const int* in_sizes, int n_in,
                              void* d_out, int out_size, void* d_ws, size_t ws_size,
                              hipStream_t stream) {
  const void* xs = d_in[0];
  const void* xt = d_in[1];
  const int* y = (const int*)d_in[2];
  const void* W1 = d_in[3];
  const void* b1 = d_in[4];
  const void* W2 = d_in[5];
  const void* b2 = d_in[6];
  const void* W3 = d_in[7];
  const void* b3 = d_in[8];
  const void* W4 = d_in[9];
  const void* b4 = d_in[10];

  // ---- workspace layout ----
  int* flag = (int*)d_ws;
  float* p = (float*)((char*)d_ws + 256);
  float* W1r = p;    p += 27 * 64;
  float* W2r = p;    p += 576 * 64;
  float* W3r = p;    p += 576 * 64;
  float* W4r = p;    p += 576 * 64;
  float* protos = p; p += BB * CC * DD;
  float* pn = p;     p += BB * CC * DD;
  float* embS = p;   p += (size_t)NSUP * DD;
  // per-image chunk buffers: conv1/2/3 outputs + target emb
  const size_t perImgF = (size_t)64 * (1764 + 441 + 121) + DD;
  const size_t fixedF = (size_t)(p - (float*)((char*)d_ws + 256));
  int CH = 1;
  const int cands[6] = {50, 25, 10, 5, 2, 1};
  for (int k = 0; k < 6; ++k) {
    if (256 + (fixedF + (size_t)cands[k] * perImgF) * 4 <= ws_size) { CH = cands[k]; break; }
  }
  float* A = p;   p += (size_t)CH * 64 * 1764;
  float* Bc = p;  p += (size_t)CH * 64 * 441;
  float* D3 = p;  p += (size_t)CH * 64 * 121;
  float* E = p;   /* p += (size_t)CH * DD; */

  // 1. dtype probe on W2 (36864 halfwords = full bf16 buffer / first half of fp32)
  fsc_probe_dtype_k<<<1, 256, 0, stream>>>((const unsigned short*)W2, 64 * 64 * 9, flag);

  // 2. repack weights -> fp32 [Cin*9][64]
  fsc_repack_w_k<<<fsc_cdiv(64 * 3 * 9, 256), 256, 0, stream>>>(W1, W1r, 3, flag);
  fsc_repack_w_k<<<fsc_cdiv(64 * 64 * 9, 256), 256, 0, stream>>>(W2, W2r, 64, flag);
  fsc_repack_w_k<<<fsc_cdiv(64 * 64 * 9, 256), 256, 0, stream>>>(W3, W3r, 64, flag);
  fsc_repack_w_k<<<fsc_cdiv(64 * 64 * 9, 256), 256, 0, stream>>>(W4, W4r, 64, flag);

  // 3. support set -> embS
  for (int off = 0; off < NSUP; off += CH) {
    const int n = (NSUP - off) < CH ? (NSUP - off) : CH;
    fsc_conv1_k<<<dim3(fsc_cdiv(n * 1764, 256), 1), 256, 0, stream>>>(
        xs, (size_t)off * 3 * 84 * 84, W1r, b1, A, n, flag);
    fsc_conv2_k<<<dim3(fsc_cdiv(n * 441, 256), 2), 256, 0, stream>>>(A, W2r, b2, Bc, n, flag);
    fsc_conv3_k<<<dim3(fsc_cdiv(n * 121, 256), 4), 256, 0, stream>>>(Bc, W3r, b3, D3, n, flag);
    fsc_conv4_k<<<dim3(fsc_cdiv(n * 36, 256), 4), 256, 0, stream>>>(
        D3, W4r, b4, embS + (size_t)off * DD, n, flag);
  }

  // 4. prototypes + normalize
  fsc_proto_k<<<fsc_cdiv(BB * CC * DD, 256), 256, 0, stream>>>(embS, y, protos);
  fsc_pnorm_k<<<BB * CC, 256, 0, stream>>>(protos, pn);

  // 5. target set -> per-chunk emb -> preds
  for (int off = 0; off < NTGT; off += CH) {
    const int n = (NTGT - off) < CH ? (NTGT - off) : CH;
    fsc_conv1_k<<<dim3(fsc_cdiv(n * 1764, 256), 1), 256, 0, stream>>>(
        xt, (size_t)off * 3 * 84 * 84, W1r, b1, A, n, flag);
    fsc_conv2_k<<<dim3(fsc_cdiv(n * 441, 256), 2), 256, 0, stream>>>(A, W2r, b2, Bc, n, flag);
    fsc_conv3_k<<<dim3(fsc_cdiv(n * 121, 256), 4), 256, 0, stream>>>(Bc, W3r, b3, D3, n, flag);
    fsc_conv4_k<<<dim3(fsc_cdiv(n * 36, 256), 4), 256, 0, stream>>>(D3, W4r, b4, E, n, flag);
    fsc_preds_k<<<n, 256, 0, stream>>>(E, pn, d_out, off, flag);
  }
}

// Round 4
// 2113.575 us; speedup vs baseline: 4.2450x; 4.2450x over previous
//
#include <hip/hip_runtime.h>
#include <hip/hip_bf16.h>

// Few-shot matching-network head + Conv4 backbone (MI355X, gfx950). Round 4.
//
// R3 passed (absmax 0.0; inputs fp32, output fp32, probe chose correctly) but at
// 8972 us: ~800 micro-dispatches, conv2 @ 7.85% occupancy / 14% VALUBusy.
// This round: large-grid restructure within the ~33 MB workspace budget:
//  - bf16 intermediate activations (halved footprint/BW; fp32 accumulation),
//  - chunked conv1->conv2 (CH~64 imgs), conv3 output stored FULL batch,
//  - conv4 + head full-batch; emb aliases the dead chunk buffers,
//  - NACC/groups per layer tuned for >=70k threads per dispatch.

#define BB 8
#define SS 25
#define TT 75
#define CC 5
#define DD 2304
#define NSUP 200
#define NTGT 600
#define NTOT 800
#define EPSF 1e-8f

__device__ __forceinline__ float load_ext(const void* p, size_t idx, int isf32) {
  if (isf32) return ((const float*)p)[idx];
  unsigned short u = ((const unsigned short*)p)[idx];
  union { unsigned int i; float f; } v;
  v.i = ((unsigned int)u) << 16;
  return v.f;
}

// ---- dtype probe (proven in r3): flag=1 => external data is fp32 ----
__global__ void fsc_probe_dtype_k(const unsigned short* __restrict__ w2raw,
                                  int nelems, int* __restrict__ flag) {
  __shared__ int cnt;
  if (threadIdx.x == 0) cnt = 0;
  __syncthreads();
  int local = 0;
  for (int i = threadIdx.x; i < nelems; i += 256) {
    unsigned short u = w2raw[i];
    int ex = (u >> 7) & 0xFF;
    if (ex != 0 && (ex < 0x69 || ex > 0x84)) local++;
  }
  atomicAdd(&cnt, local);
  __syncthreads();
  if (threadIdx.x == 0) *flag = (cnt > nelems / 8) ? 1 : 0;
}

// ---- weight repack: OIHW [64][CIN][3][3] -> fp32 [CIN*9][64] ----
__global__ void fsc_repack_w_k(const void* __restrict__ W, float* __restrict__ Wr,
                               int CIN, const int* __restrict__ flag) {
  const int isf32 = *flag;
  int i = blockIdx.x * blockDim.x + threadIdx.x;
  int total = 64 * CIN * 9;
  if (i >= total) return;
  int co = i / (CIN * 9);
  int r = i - co * CIN * 9;
  Wr[r * 64 + co] = load_ext(W, i, isf32);
}

// ---- conv1: ext [n][3][84][84] -> bf16 [n][64][42][42], pad (0,1), 64 acc ----
__global__ void fsc_conv1_k(const void* __restrict__ x, size_t base,
                            const float* __restrict__ Wr, const void* __restrict__ bias,
                            __hip_bfloat16* __restrict__ out, int N,
                            const int* __restrict__ flag) {
  const int isf32 = *flag;
  int idx = blockIdx.x * blockDim.x + threadIdx.x;
  const int n = idx / 1764;
  const int sp = idx - n * 1764;
  if (n >= N) return;
  const int ho = sp / 42, wo = sp - ho * 42;
  float acc[64];
#pragma unroll
  for (int j = 0; j < 64; ++j) acc[j] = 0.f;
  const size_t inn = base + (size_t)n * 21168;  // 3*84*84
  for (int ci = 0; ci < 3; ++ci) {
#pragma unroll
    for (int kh = 0; kh < 3; ++kh) {
      const int hi = 2 * ho + kh;
      const bool hok = hi < 84;
#pragma unroll
      for (int kw = 0; kw < 3; ++kw) {
        const int wi = 2 * wo + kw;
        const float val =
            (hok && wi < 84) ? load_ext(x, inn + (ci * 84 + hi) * 84 + wi, isf32) : 0.f;
        const float* wp = Wr + ((ci * 3 + kh) * 3 + kw) * 64;
#pragma unroll
        for (int j = 0; j < 64; ++j) acc[j] = fmaf(wp[j], val, acc[j]);
      }
    }
  }
  __hip_bfloat16* o = out + (size_t)n * 112896 + sp;  // 64*1764
#pragma unroll
  for (int j = 0; j < 64; ++j) {
    float r = acc[j] + load_ext(bias, j, isf32);
    o[(size_t)j * 1764] = __float2bfloat16(r > 0.f ? r : 0.f);
  }
}

// ---- conv2: bf16 [n][64][42][42] -> bf16 [n][64][21][21], pad (0,1); 16 acc x 4 grp ----
__global__ void fsc_conv2_k(const __hip_bfloat16* __restrict__ in,
                            const float* __restrict__ Wr, const void* __restrict__ bias,
                            __hip_bfloat16* __restrict__ out, int N,
                            const int* __restrict__ flag) {
  const int isf32 = *flag;
  const int g = blockIdx.y;  // 0..3
  int idx = blockIdx.x * blockDim.x + threadIdx.x;
  const int n = idx / 441;
  const int sp = idx - n * 441;
  if (n >= N) return;
  const int ho = sp / 21, wo = sp - ho * 21;
  float acc[16];
#pragma unroll
  for (int j = 0; j < 16; ++j) acc[j] = 0.f;
  const __hip_bfloat16* inn = in + (size_t)n * 112896;
  const float* wbase = Wr + g * 16;
  for (int ci = 0; ci < 64; ++ci) {
#pragma unroll
    for (int kh = 0; kh < 3; ++kh) {
      const int hi = 2 * ho + kh;
      const bool hok = hi < 42;
#pragma unroll
      for (int kw = 0; kw < 3; ++kw) {
        const int wi = 2 * wo + kw;
        const float val =
            (hok && wi < 42) ? __bfloat162float(inn[(ci * 42 + hi) * 42 + wi]) : 0.f;
        const float* wp = wbase + ((ci * 3 + kh) * 3 + kw) * 64;
#pragma unroll
        for (int j = 0; j < 16; ++j) acc[j] = fmaf(wp[j], val, acc[j]);
      }
    }
  }
  __hip_bfloat16* o = out + ((size_t)n * 64 + g * 16) * 441 + sp;
#pragma unroll
  for (int j = 0; j < 16; ++j) {
    float r = acc[j] + load_ext(bias, g * 16 + j, isf32);
    o[(size_t)j * 441] = __float2bfloat16(r > 0.f ? r : 0.f);
  }
}

// ---- conv3: bf16 [n][64][21][21] -> bf16 chunk of c3full [img][64][11][11], pad 1;
//      8 acc x 8 grp. `out` pre-offset to this chunk's first image. ----
__global__ void fsc_conv3_k(const __hip_bfloat16* __restrict__ in,
                            const float* __restrict__ Wr, const void* __restrict__ bias,
                            __hip_bfloat16* __restrict__ out, int N,
                            const int* __restrict__ flag) {
  const int isf32 = *flag;
  const int g = blockIdx.y;  // 0..7
  int idx = blockIdx.x * blockDim.x + threadIdx.x;
  const int n = idx / 121;
  const int sp = idx - n * 121;
  if (n >= N) return;
  const int ho = sp / 11, wo = sp - ho * 11;
  float acc[8];
#pragma unroll
  for (int j = 0; j < 8; ++j) acc[j] = 0.f;
  const __hip_bfloat16* inn = in + (size_t)n * 28224;  // 64*441
  const float* wbase = Wr + g * 8;
  for (int ci = 0; ci < 64; ++ci) {
#pragma unroll
    for (int kh = 0; kh < 3; ++kh) {
      const int hi = 2 * ho + kh - 1;
      const bool hok = (hi >= 0 && hi < 21);
#pragma unroll
      for (int kw = 0; kw < 3; ++kw) {
        const int wi = 2 * wo + kw - 1;
        const float val = (hok && wi >= 0 && wi < 21)
                              ? __bfloat162float(inn[(ci * 21 + hi) * 21 + wi]) : 0.f;
        const float* wp = wbase + ((ci * 3 + kh) * 3 + kw) * 64;
#pragma unroll
        for (int j = 0; j < 8; ++j) acc[j] = fmaf(wp[j], val, acc[j]);
      }
    }
  }
  __hip_bfloat16* o = out + ((size_t)n * 64 + g * 8) * 121 + sp;
#pragma unroll
  for (int j = 0; j < 8; ++j) {
    float r = acc[j] + load_ext(bias, g * 8 + j, isf32);
    o[(size_t)j * 121] = __float2bfloat16(r > 0.f ? r : 0.f);
  }
}

// ---- conv4 FULL batch: bf16 [800][64][11][11] -> fp32 emb [800][2304], pad 1;
//      8 acc x 8 grp (230k threads). ----
__global__ void fsc_conv4_k(const __hip_bfloat16* __restrict__ in,
                            const float* __restrict__ Wr, const void* __restrict__ bias,
                            float* __restrict__ emb, const int* __restrict__ flag) {
  const int isf32 = *flag;
  const int g = blockIdx.y;  // 0..7
  int idx = blockIdx.x * blockDim.x + threadIdx.x;
  const int n = idx / 36;
  const int sp = idx - n * 36;
  if (n >= NTOT) return;
  const int ho = sp / 6, wo = sp - ho * 6;
  float acc[8];
#pragma unroll
  for (int j = 0; j < 8; ++j) acc[j] = 0.f;
  const __hip_bfloat16* inn = in + (size_t)n * 7744;  // 64*121
  const float* wbase = Wr + g * 8;
  for (int ci = 0; ci < 64; ++ci) {
#pragma unroll
    for (int kh = 0; kh < 3; ++kh) {
      const int hi = 2 * ho + kh - 1;
      const bool hok = (hi >= 0 && hi < 11);
#pragma unroll
      for (int kw = 0; kw < 3; ++kw) {
        const int wi = 2 * wo + kw - 1;
        const float val = (hok && wi >= 0 && wi < 11)
                              ? __bfloat162float(inn[(ci * 11 + hi) * 11 + wi]) : 0.f;
        const float* wp = wbase + ((ci * 3 + kh) * 3 + kw) * 64;
#pragma unroll
        for (int j = 0; j < 8; ++j) acc[j] = fmaf(wp[j], val, acc[j]);
      }
    }
  }
  float* o = emb + (size_t)n * DD + (g * 8) * 36 + sp;
#pragma unroll
  for (int j = 0; j < 8; ++j) {
    float r = acc[j] + load_ext(bias, g * 8 + j, isf32);
    o[(size_t)j * 36] = r > 0.f ? r : 0.f;
  }
}

// ---- head: prototypes, normalize, cosine logits (proven in r3) ----
__global__ void fsc_proto_k(const float* __restrict__ emb_s, const int* __restrict__ y,
                            float* __restrict__ protos) {
  int i = blockIdx.x * blockDim.x + threadIdx.x;
  if (i >= BB * CC * DD) return;
  int d = i % DD;
  int bc = i / DD;
  int c = bc % CC;
  int b = bc / CC;
  float sum = 0.f;
  for (int s = 0; s < SS; ++s) {
    if (y[b * SS + s] % CC == c) sum += emb_s[(size_t)(b * SS + s) * DD + d];
  }
  protos[i] = sum * 0.2f;
}

__global__ void fsc_pnorm_k(const float* __restrict__ protos, float* __restrict__ pn) {
  __shared__ float red[4];
  __shared__ float inv;
  const int bc = blockIdx.x;
  const float* p = protos + (size_t)bc * DD;
  float ss = 0.f;
  for (int d = threadIdx.x; d < DD; d += 256) { float v = p[d]; ss += v * v; }
#pragma unroll
  for (int off = 32; off > 0; off >>= 1) ss += __shfl_down(ss, off);
  if ((threadIdx.x & 63) == 0) red[threadIdx.x >> 6] = ss;
  __syncthreads();
  if (threadIdx.x == 0) {
    float nrm = sqrtf(red[0] + red[1] + red[2] + red[3]);
    nrm = nrm > EPSF ? nrm : EPSF;
    inv = 1.f / nrm;
  }
  __syncthreads();
  float sc = inv;
  for (int d = threadIdx.x; d < DD; d += 256) pn[(size_t)bc * DD + d] = p[d] * sc;
}

__global__ void fsc_preds_k(const float* __restrict__ emb_t, const float* __restrict__ pn,
                            void* __restrict__ out, const int* __restrict__ flag) {
  __shared__ float red[4][6];
  __shared__ float fin[6];
  const int isf32 = *flag;
  const int bt = blockIdx.x;  // 0..599
  const int b = bt / TT;
  const float* et = emb_t + (size_t)bt * DD;
  float e[9];
#pragma unroll
  for (int k = 0; k < 9; ++k) e[k] = et[threadIdx.x + 256 * k];
  float vals[6];
  {
    float ss = 0.f;
#pragma unroll
    for (int k = 0; k < 9; ++k) ss += e[k] * e[k];
    vals[0] = ss;
  }
  const float* pb = pn + (size_t)b * CC * DD;
#pragma unroll
  for (int c = 0; c < CC; ++c) {
    float s = 0.f;
#pragma unroll
    for (int k = 0; k < 9; ++k) s += e[k] * pb[(size_t)c * DD + threadIdx.x + 256 * k];
    vals[1 + c] = s;
  }
#pragma unroll
  for (int v = 0; v < 6; ++v) {
#pragma unroll
    for (int off = 32; off > 0; off >>= 1) vals[v] += __shfl_down(vals[v], off);
  }
  if ((threadIdx.x & 63) == 0) {
#pragma unroll
    for (int v = 0; v < 6; ++v) red[threadIdx.x >> 6][v] = vals[v];
  }
  __syncthreads();
  if (threadIdx.x < 6)
    fin[threadIdx.x] = red[0][threadIdx.x] + red[1][threadIdx.x] +
                       red[2][threadIdx.x] + red[3][threadIdx.x];
  __syncthreads();
  if (threadIdx.x < CC) {
    float nt = sqrtf(fin[0]);
    nt = nt > EPSF ? nt : EPSF;
    float r = fin[1 + threadIdx.x] / nt;
    if (isf32) ((float*)out)[(size_t)bt * CC + threadIdx.x] = r;
    else ((__hip_bfloat16*)out)[(size_t)bt * CC + threadIdx.x] = __float2bfloat16(r);
  }
}

static inline int fsc_cdiv(int a, int b) { return (a + b - 1) / b; }

extern "C" void kernel_launch(void* const* d_in, const int* in_sizes, int n_in,
                              void* d_out, int out_size, void* d_ws, size_t ws_size,
                              hipStream_t stream) {
  const void* xs = d_in[0];
  const void* xt = d_in[1];
  const int* y = (const int*)d_in[2];
  const void* W1 = d_in[3];
  const void* b1 = d_in[4];
  const void* W2 = d_in[5];
  const void* b2 = d_in[6];
  const void* W3 = d_in[7];
  const void* b3 = d_in[8];
  const void* W4 = d_in[9];
  const void* b4 = d_in[10];

  // ---- workspace layout ----
  char* w = (char*)d_ws;
  int* flag = (int*)w;              w += 256;
  float* W1r = (float*)w;           w += 27 * 64 * 4;
  float* W2r = (float*)w;           w += 576 * 64 * 4;
  float* W3r = (float*)w;           w += 576 * 64 * 4;
  float* W4r = (float*)w;           w += 576 * 64 * 4;
  float* protos = (float*)w;        w += (size_t)BB * CC * DD * 4;
  float* pn = (float*)w;            w += (size_t)BB * CC * DD * 4;
  __hip_bfloat16* c3full = (__hip_bfloat16*)w;  w += (size_t)NTOT * 7744 * 2;  // 12.4 MB
  char* chunk0 = w;
  const size_t fixedB = (size_t)(w - (char*)d_ws);
  const size_t perImgB = (size_t)(112896 + 28224) * 2;  // conv1 + conv2 bufs, bf16

  int CH = 27;  // floor: emb alias needs CH*perImgB >= 800*2304*4 (7.37 MB)
  const int cands[9] = {256, 192, 128, 96, 80, 64, 48, 32, 27};
  for (int k = 0; k < 9; ++k) {
    if (fixedB + (size_t)cands[k] * perImgB <= ws_size) { CH = cands[k]; break; }
  }
  __hip_bfloat16* A = (__hip_bfloat16*)chunk0;                       // [CH][64][42][42]
  __hip_bfloat16* Bc = (__hip_bfloat16*)(chunk0 + (size_t)CH * 112896 * 2);  // [CH][64][21][21]
  float* emb = (float*)chunk0;  // phase-2 alias over dead chunk buffers, [800][2304]

  // 1. dtype probe + weight repack
  fsc_probe_dtype_k<<<1, 256, 0, stream>>>((const unsigned short*)W2, 64 * 64 * 9, flag);
  fsc_repack_w_k<<<fsc_cdiv(64 * 3 * 9, 256), 256, 0, stream>>>(W1, W1r, 3, flag);
  fsc_repack_w_k<<<fsc_cdiv(64 * 64 * 9, 256), 256, 0, stream>>>(W2, W2r, 64, flag);
  fsc_repack_w_k<<<fsc_cdiv(64 * 64 * 9, 256), 256, 0, stream>>>(W3, W3r, 64, flag);
  fsc_repack_w_k<<<fsc_cdiv(64 * 64 * 9, 256), 256, 0, stream>>>(W4, W4r, 64, flag);

  // 2. conv1 -> conv2 -> conv3 chunked; conv3 writes full-batch buffer
  auto run_set = [&](const void* x, int count, int gbase) {
    for (int off = 0; off < count; off += CH) {
      const int n = (count - off) < CH ? (count - off) : CH;
      fsc_conv1_k<<<dim3(fsc_cdiv(n * 1764, 256), 1), 256, 0, stream>>>(
          x, (size_t)off * 21168, W1r, b1, A, n, flag);
      fsc_conv2_k<<<dim3(fsc_cdiv(n * 441, 256), 4), 256, 0, stream>>>(
          A, W2r, b2, Bc, n, flag);
      fsc_conv3_k<<<dim3(fsc_cdiv(n * 121, 256), 8), 256, 0, stream>>>(
          Bc, W3r, b3, c3full + (size_t)(gbase + off) * 7744, n, flag);
    }
  };
  run_set(xs, NSUP, 0);
  run_set(xt, NTGT, NSUP);

  // 3. conv4 full batch -> emb (aliased over chunk area; chunk bufs are dead now)
  fsc_conv4_k<<<dim3(fsc_cdiv(NTOT * 36, 256), 8), 256, 0, stream>>>(
      c3full, W4r, b4, emb, flag);

  // 4. head
  fsc_proto_k<<<fsc_cdiv(BB * CC * DD, 256), 256, 0, stream>>>(emb, y, protos);
  fsc_pnorm_k<<<BB * CC, 256, 0, stream>>>(protos, pn);
  fsc_preds_k<<<NTGT, 256, 0, stream>>>(emb + (size_t)NSUP * DD, pn, d_out, flag);
}

// Round 5
// 1039.225 us; speedup vs baseline: 8.6335x; 2.0338x over previous
//
#include <hip/hip_runtime.h>
#include <hip/hip_bf16.h>

// Few-shot matching-network head + Conv4 backbone (MI355X, gfx950). Round 5.
//
// R4: 2114 us, MfmaUtil=0 (all fp32 VALU). This round: conv2/3/4 (35 of 40
// GFLOP) via implicit-GEMM mfma_f32_16x16x32_bf16:
//  - activations in NHWC bf16 with 1-px ZERO border (SAME pad -> no branches);
//    B-frag = one global_load_dwordx4/lane (8 consecutive ci), quads of one
//    column cover a full 64B line.
//  - weights pre-repacked into exact A-fragment order; A-frag = dwordx4, L2-hot.
//  - K = 9 taps x 2 ci-halves = 18 unrolled MFMA steps; wave = 64 cout x 16 cols.
//  - conv4 emits fp32 emb in NHWC-permuted order: head is permutation-invariant.
// conv1 stays direct VALU (K=27), writing NHWC-padded bf16.

#define BB 8
#define SS 25
#define TT 75
#define CC 5
#define DD 2304
#define NSUP 200
#define NTGT 600
#define NTOT 800
#define EPSF 1e-8f

typedef __attribute__((ext_vector_type(8))) short bf16x8;
typedef __attribute__((ext_vector_type(4))) float f32x4;

__device__ __forceinline__ float load_ext(const void* p, size_t idx, int isf32) {
  if (isf32) return ((const float*)p)[idx];
  unsigned short u = ((const unsigned short*)p)[idx];
  union { unsigned int i; float f; } v;
  v.i = ((unsigned int)u) << 16;
  return v.f;
}

// ---- dtype probe (proven r3/r4): flag=1 => external data is fp32 ----
__global__ void fsc_probe_dtype_k(const unsigned short* __restrict__ w2raw,
                                  int nelems, int* __restrict__ flag) {
  __shared__ int cnt;
  if (threadIdx.x == 0) cnt = 0;
  __syncthreads();
  int local = 0;
  for (int i = threadIdx.x; i < nelems; i += 256) {
    unsigned short u = w2raw[i];
    int ex = (u >> 7) & 0xFF;
    if (ex != 0 && (ex < 0x69 || ex > 0x84)) local++;
  }
  atomicAdd(&cnt, local);
  __syncthreads();
  if (threadIdx.x == 0) *flag = (cnt > nelems / 8) ? 1 : 0;
}

// ---- conv1 weight repack: OIHW [64][3][3][3] -> fp32 [27][64] ----
__global__ void fsc_repack_w1_k(const void* __restrict__ W, float* __restrict__ Wr,
                                const int* __restrict__ flag) {
  const int isf32 = *flag;
  int i = blockIdx.x * blockDim.x + threadIdx.x;
  if (i >= 64 * 27) return;
  int co = i / 27;
  int r = i - co * 27;
  Wr[r * 64 + co] = load_ext(W, i, isf32);
}

// ---- MFMA weight repack: OIHW [64][64][3][3] -> bf16 A-fragment order:
//      [kk=18][t=4][lane=64][j=8], co = t*16 + (lane&15),
//      ci = (kk&1)*32 + (lane>>4)*8 + j, (kh,kw) = decode(kk>>1). ----
__global__ void fsc_repack_wm_k(const void* __restrict__ W,
                                __hip_bfloat16* __restrict__ Wf,
                                const int* __restrict__ flag) {
  const int isf32 = *flag;
  int o = blockIdx.x * blockDim.x + threadIdx.x;
  if (o >= 36864) return;
  int j = o & 7;
  int lane = (o >> 3) & 63;
  int t = (o >> 9) & 3;
  int kk = o >> 11;       // 0..17
  int s = kk & 1;
  int khw = kk >> 1;      // kh*3+kw
  int kh = khw / 3, kw = khw - kh * 3;
  int co = t * 16 + (lane & 15);
  int ci = s * 32 + (lane >> 4) * 8 + j;
  float v = load_ext(W, (size_t)((co * 64 + ci) * 3 + kh) * 3 + kw, isf32);
  Wf[o] = __float2bfloat16(v);
}

// ---- zero the 1-px border of an NHWC-padded [N][P][P][64] bf16 buffer ----
template <int P>
__global__ void fsc_zero_border_k(__hip_bfloat16* __restrict__ buf, int N) {
  int i = blockIdx.x * blockDim.x + threadIdx.x;
  const int RP = 4 * P - 4;
  if (i >= N * RP * 64) return;
  int c = i & 63;
  int r = (i >> 6) % RP;
  int n = (i >> 6) / RP;
  int row, colp;
  if (r < P) { row = 0; colp = r; }
  else if (r < 2 * P) { row = P - 1; colp = r - P; }
  else if (r < 3 * P - 2) { row = r - 2 * P + 1; colp = 0; }
  else { row = r - (3 * P - 2) + 1; colp = P - 1; }
  buf[(((size_t)n * P + row) * P + colp) * 64 + c] = __float2bfloat16(0.f);
}

// ---- conv1: ext [n][3][84][84] -> bf16 NHWC-padded [n][44][44][64], pad (0,1) ----
__global__ void fsc_conv1_k(const void* __restrict__ x, size_t base,
                            const float* __restrict__ Wr, const void* __restrict__ bias,
                            __hip_bfloat16* __restrict__ out, int N,
                            const int* __restrict__ flag) {
  const int isf32 = *flag;
  int idx = blockIdx.x * blockDim.x + threadIdx.x;
  const int n = idx / 1764;
  const int sp = idx - n * 1764;
  if (n >= N) return;
  const int ho = sp / 42, wo = sp - ho * 42;
  float acc[64];
#pragma unroll
  for (int j = 0; j < 64; ++j) acc[j] = 0.f;
  const size_t inn = base + (size_t)n * 21168;  // 3*84*84
  for (int ci = 0; ci < 3; ++ci) {
#pragma unroll
    for (int kh = 0; kh < 3; ++kh) {
      const int hi = 2 * ho + kh;
      const bool hok = hi < 84;
#pragma unroll
      for (int kw = 0; kw < 3; ++kw) {
        const int wi = 2 * wo + kw;
        const float val =
            (hok && wi < 84) ? load_ext(x, inn + (ci * 84 + hi) * 84 + wi, isf32) : 0.f;
        const float* wp = Wr + ((ci * 3 + kh) * 3 + kw) * 64;
#pragma unroll
        for (int j = 0; j < 64; ++j) acc[j] = fmaf(wp[j], val, acc[j]);
      }
    }
  }
  __hip_bfloat16* o = out + (size_t)n * 123904 + ((size_t)(ho + 1) * 44 + (wo + 1)) * 64;
#pragma unroll
  for (int j = 0; j < 64; ++j) {
    float r = acc[j] + load_ext(bias, j, isf32);
    o[j] = __float2bfloat16(r > 0.f ? r : 0.f);
  }
}

// ---- implicit-GEMM MFMA conv: 64ci -> 64co, 3x3 stride 2.
// in: bf16 NHWC-padded [img][PWI][PWI][64] (zero border).
// Wf: A-frag repacked weights. ROFF = 1 - pad_top (conv2:1, conv3/4:0).
// EMB_OUT=false: out bf16 NHWC-padded [img][PWO][PWO][64] (+bias, ReLU).
// EMB_OUT=true : out fp32 [img][HO*HO*64] flat (emb rows, permuted vs NCHW - OK).
// Wave = 16 output columns x 64 couts; no LDS, no __syncthreads.
template <int HO, int PWI, int PWO, int ROFF, bool EMB_OUT>
__global__ void fsc_convm_k(const __hip_bfloat16* __restrict__ in,
                            const __hip_bfloat16* __restrict__ Wf,
                            const void* __restrict__ bias, void* __restrict__ out,
                            int N, const int* __restrict__ flag) {
  constexpr int TPI = (HO * HO + 15) / 16;
  const int wid = blockIdx.x * 4 + (threadIdx.x >> 6);
  const int img = wid / TPI;
  if (img >= N) return;
  const int tl = wid - img * TPI;
  const int lane = threadIdx.x & 63;
  const int nidx = lane & 15, quad = lane >> 4;
  int col = tl * 16 + nidx;
  const bool valid = col < HO * HO;
  if (!valid) col = HO * HO - 1;
  const int ho = col / HO, wo = col - ho * HO;

  // B source: all 18 k-step addresses are constant offsets from this.
  const __hip_bfloat16* bsrc =
      in + (((size_t)img * PWI + (2 * ho + ROFF)) * PWI + (2 * wo + ROFF)) * 64 + quad * 8;
  const __hip_bfloat16* asrc = Wf + lane * 8;

  f32x4 acc[4];
#pragma unroll
  for (int t = 0; t < 4; ++t) acc[t] = (f32x4){0.f, 0.f, 0.f, 0.f};

#pragma unroll
  for (int kk = 0; kk < 18; ++kk) {
    const int s = kk & 1;
    const int khw = kk >> 1;
    const int kh = khw / 3, kw = khw - kh * 3;
    bf16x8 b = *(const bf16x8*)(const void*)(bsrc + ((kh * PWI + kw) * 64 + s * 32));
#pragma unroll
    for (int t = 0; t < 4; ++t) {
      bf16x8 a = *(const bf16x8*)(const void*)(asrc + (kk * 4 + t) * 512);
      acc[t] = __builtin_amdgcn_mfma_f32_16x16x32_bf16(a, b, acc[t], 0, 0, 0);
    }
  }

  const int isf32 = *flag;
#pragma unroll
  for (int t = 0; t < 4; ++t) {
    float v[4];
#pragma unroll
    for (int r = 0; r < 4; ++r) {
      const int cout = t * 16 + quad * 4 + r;
      float x = acc[t][r] + load_ext(bias, cout, isf32);
      v[r] = x > 0.f ? x : 0.f;
    }
    if (valid) {
      if (EMB_OUT) {
        float* o = (float*)out + ((size_t)img * HO * HO + col) * 64 + t * 16 + quad * 4;
        *(f32x4*)(void*)o = (f32x4){v[0], v[1], v[2], v[3]};
      } else {
        __hip_bfloat16* o = (__hip_bfloat16*)out +
                            (((size_t)img * PWO + (ho + 1)) * PWO + (wo + 1)) * 64 +
                            t * 16 + quad * 4;
        union { unsigned short u[4]; uint2 w; } pk;
#pragma unroll
        for (int r = 0; r < 4; ++r) pk.u[r] = __bfloat16_as_ushort(__float2bfloat16(v[r]));
        *(uint2*)(void*)o = pk.w;
      }
    }
  }
}

// ---- head (proven r3/r4; emb rows are NHWC-permuted - head is perm-invariant) ----
__global__ void fsc_proto_k(const float* __restrict__ emb_s, const int* __restrict__ y,
                            float* __restrict__ protos) {
  int i = blockIdx.x * blockDim.x + threadIdx.x;
  if (i >= BB * CC * DD) return;
  int d = i % DD;
  int bc = i / DD;
  int c = bc % CC;
  int b = bc / CC;
  float sum = 0.f;
  for (int s = 0; s < SS; ++s) {
    if (y[b * SS + s] % CC == c) sum += emb_s[(size_t)(b * SS + s) * DD + d];
  }
  protos[i] = sum * 0.2f;
}

__global__ void fsc_pnorm_k(const float* __restrict__ protos, float* __restrict__ pn) {
  __shared__ float red[4];
  __shared__ float inv;
  const int bc = blockIdx.x;
  const float* p = protos + (size_t)bc * DD;
  float ss = 0.f;
  for (int d = threadIdx.x; d < DD; d += 256) { float v = p[d]; ss += v * v; }
#pragma unroll
  for (int off = 32; off > 0; off >>= 1) ss += __shfl_down(ss, off);
  if ((threadIdx.x & 63) == 0) red[threadIdx.x >> 6] = ss;
  __syncthreads();
  if (threadIdx.x == 0) {
    float nrm = sqrtf(red[0] + red[1] + red[2] + red[3]);
    nrm = nrm > EPSF ? nrm : EPSF;
    inv = 1.f / nrm;
  }
  __syncthreads();
  float sc = inv;
  for (int d = threadIdx.x; d < DD; d += 256) pn[(size_t)bc * DD + d] = p[d] * sc;
}

__global__ void fsc_preds_k(const float* __restrict__ emb_t, const float* __restrict__ pn,
                            void* __restrict__ out, const int* __restrict__ flag) {
  __shared__ float red[4][6];
  __shared__ float fin[6];
  const int isf32 = *flag;
  const int bt = blockIdx.x;
  const int b = bt / TT;
  const float* et = emb_t + (size_t)bt * DD;
  float e[9];
#pragma unroll
  for (int k = 0; k < 9; ++k) e[k] = et[threadIdx.x + 256 * k];
  float vals[6];
  {
    float ss = 0.f;
#pragma unroll
    for (int k = 0; k < 9; ++k) ss += e[k] * e[k];
    vals[0] = ss;
  }
  const float* pb = pn + (size_t)b * CC * DD;
#pragma unroll
  for (int c = 0; c < CC; ++c) {
    float s = 0.f;
#pragma unroll
    for (int k = 0; k < 9; ++k) s += e[k] * pb[(size_t)c * DD + threadIdx.x + 256 * k];
    vals[1 + c] = s;
  }
#pragma unroll
  for (int v = 0; v < 6; ++v) {
#pragma unroll
    for (int off = 32; off > 0; off >>= 1) vals[v] += __shfl_down(vals[v], off);
  }
  if ((threadIdx.x & 63) == 0) {
#pragma unroll
    for (int v = 0; v < 6; ++v) red[threadIdx.x >> 6][v] = vals[v];
  }
  __syncthreads();
  if (threadIdx.x < 6)
    fin[threadIdx.x] = red[0][threadIdx.x] + red[1][threadIdx.x] +
                       red[2][threadIdx.x] + red[3][threadIdx.x];
  __syncthreads();
  if (threadIdx.x < CC) {
    float nt = sqrtf(fin[0]);
    nt = nt > EPSF ? nt : EPSF;
    float r = fin[1 + threadIdx.x] / nt;
    if (isf32) ((float*)out)[(size_t)bt * CC + threadIdx.x] = r;
    else ((__hip_bfloat16*)out)[(size_t)bt * CC + threadIdx.x] = __float2bfloat16(r);
  }
}

static inline int fsc_cdiv(int a, int b) { return (a + b - 1) / b; }

extern "C" void kernel_launch(void* const* d_in, const int* in_sizes, int n_in,
                              void* d_out, int out_size, void* d_ws, size_t ws_size,
                              hipStream_t stream) {
  const void* xs = d_in[0];
  const void* xt = d_in[1];
  const int* y = (const int*)d_in[2];
  const void* W1 = d_in[3];
  const void* b1 = d_in[4];
  const void* W2 = d_in[5];
  const void* b2 = d_in[6];
  const void* W3 = d_in[7];
  const void* b3 = d_in[8];
  const void* W4 = d_in[9];
  const void* b4 = d_in[10];

  // ---- workspace layout ----
  char* w = (char*)d_ws;
  int* flag = (int*)w;                     w += 256;
  float* W1r = (float*)w;                  w += 27 * 64 * 4;          // 6.9 KB
  __hip_bfloat16* Wf2 = (__hip_bfloat16*)w; w += 36864 * 2;           // 72 KB
  __hip_bfloat16* Wf3 = (__hip_bfloat16*)w; w += 36864 * 2;
  __hip_bfloat16* Wf4 = (__hip_bfloat16*)w; w += 36864 * 2;
  float* protos = (float*)w;               w += (size_t)BB * CC * DD * 4;
  float* pn = (float*)w;                   w += (size_t)BB * CC * DD * 4;
  __hip_bfloat16* c3full = (__hip_bfloat16*)w; w += (size_t)NTOT * 13 * 13 * 64 * 2;  // 17.3 MB
  char* chunk0 = w;
  const size_t fixedB = (size_t)(w - (char*)d_ws);
  const size_t perImgB = ((size_t)44 * 44 * 64 + (size_t)23 * 23 * 64) * 2;  // 315,520 B

  int CH = 24;  // floor: emb alias needs CH*perImgB >= 800*2304*4
  const int cands[7] = {128, 96, 72, 64, 48, 32, 24};
  for (int k = 0; k < 7; ++k) {
    if (fixedB + (size_t)cands[k] * perImgB <= ws_size) { CH = cands[k]; break; }
  }
  __hip_bfloat16* A1 = (__hip_bfloat16*)chunk0;                                   // [CH][44][44][64]
  __hip_bfloat16* A2 = (__hip_bfloat16*)(chunk0 + (size_t)CH * 44 * 44 * 64 * 2); // [CH][23][23][64]
  float* emb = (float*)chunk0;  // phase-2 alias (chunk bufs dead), [800][2304]

  // 1. dtype probe + weight repacks
  fsc_probe_dtype_k<<<1, 256, 0, stream>>>((const unsigned short*)W2, 64 * 64 * 9, flag);
  fsc_repack_w1_k<<<fsc_cdiv(64 * 27, 256), 256, 0, stream>>>(W1, W1r, flag);
  fsc_repack_wm_k<<<fsc_cdiv(36864, 256), 256, 0, stream>>>(W2, Wf2, flag);
  fsc_repack_wm_k<<<fsc_cdiv(36864, 256), 256, 0, stream>>>(W3, Wf3, flag);
  fsc_repack_wm_k<<<fsc_cdiv(36864, 256), 256, 0, stream>>>(W4, Wf4, flag);

  // 2. zero NHWC borders (interiors fully overwritten by convs; borders stay 0)
  fsc_zero_border_k<44><<<fsc_cdiv(CH * (4 * 44 - 4) * 64, 256), 256, 0, stream>>>(A1, CH);
  fsc_zero_border_k<23><<<fsc_cdiv(CH * (4 * 23 - 4) * 64, 256), 256, 0, stream>>>(A2, CH);
  fsc_zero_border_k<13><<<fsc_cdiv(NTOT * (4 * 13 - 4) * 64, 256), 256, 0, stream>>>(c3full, NTOT);

  // 3. conv1 (VALU) -> conv2 (MFMA) -> conv3 (MFMA, into full-batch buffer), chunked
  auto run_set = [&](const void* x, int count, int gbase) {
    for (int off = 0; off < count; off += CH) {
      const int n = (count - off) < CH ? (count - off) : CH;
      fsc_conv1_k<<<fsc_cdiv(n * 1764, 256), 256, 0, stream>>>(
          x, (size_t)off * 21168, W1r, b1, A1, n, flag);
      // conv2: 44-padded -> 21x21 out in 23-padded; pad_top=0 -> ROFF=1; TPI=28
      fsc_convm_k<21, 44, 23, 1, false><<<fsc_cdiv(n * 28, 4), 256, 0, stream>>>(
          A1, Wf2, b2, A2, n, flag);
      // conv3: 23-padded -> 11x11 out in 13-padded; pad=1 -> ROFF=0; TPI=8
      fsc_convm_k<11, 23, 13, 0, false><<<fsc_cdiv(n * 8, 4), 256, 0, stream>>>(
          A2, Wf3, b3, c3full + (size_t)(gbase + off) * 13 * 13 * 64, n, flag);
    }
  };
  run_set(xs, NSUP, 0);
  run_set(xt, NTGT, NSUP);

  // 4. conv4 full batch (MFMA): 13-padded -> fp32 emb [800][2304]; TPI=3
  fsc_convm_k<6, 13, 0, 0, true><<<fsc_cdiv(NTOT * 3, 4), 256, 0, stream>>>(
      c3full, Wf4, b4, emb, NTOT, flag);

  // 5. head
  fsc_proto_k<<<fsc_cdiv(BB * CC * DD, 256), 256, 0, stream>>>(emb, y, protos);
  fsc_pnorm_k<<<BB * CC, 256, 0, stream>>>(protos, pn);
  fsc_preds_k<<<NTGT, 256, 0, stream>>>(emb + (size_t)NSUP * DD, pn, d_out, flag);
}

// Round 6
// 763.523 us; speedup vs baseline: 11.7509x; 1.3611x over previous
//
#include <hip/hip_runtime.h>
#include <hip/hip_bf16.h>

// Few-shot matching-network head + Conv4 backbone (MI355X, gfx950). Round 6.
//
// R5: 1039 us. Profile: conv1 dominates with VGPR_Count=64 + ~720 MB WRITE_SIZE
// per dispatch => acc[64] spilled to scratch (每 fmaf round-trips HBM). Fixes:
//  - conv1 split into 2 channel groups (acc[32], gridDim.y=2): no spill;
//    bf16 outputs packed 2-per-dword store.
//  - convm: 32 output cols/wave (2 B-frags share each A-frag): per k-step
//    6 loads + 8 MFMAs (was 10 + 8), 2-way MFMA ILP, acc=32 VGPR.
// Everything else (NHWC zero-border layout, frag-order weight repack, head)
// carried from r5 (absmax 0.0039, 4x under threshold).

#define BB 8
#define SS 25
#define TT 75
#define CC 5
#define DD 2304
#define NSUP 200
#define NTGT 600
#define NTOT 800
#define EPSF 1e-8f

typedef __attribute__((ext_vector_type(8))) short bf16x8;
typedef __attribute__((ext_vector_type(4))) float f32x4;

__device__ __forceinline__ float load_ext(const void* p, size_t idx, int isf32) {
  if (isf32) return ((const float*)p)[idx];
  unsigned short u = ((const unsigned short*)p)[idx];
  union { unsigned int i; float f; } v;
  v.i = ((unsigned int)u) << 16;
  return v.f;
}

// ---- dtype probe (proven r3-r5): flag=1 => external data is fp32 ----
__global__ void fsc_probe_dtype_k(const unsigned short* __restrict__ w2raw,
                                  int nelems, int* __restrict__ flag) {
  __shared__ int cnt;
  if (threadIdx.x == 0) cnt = 0;
  __syncthreads();
  int local = 0;
  for (int i = threadIdx.x; i < nelems; i += 256) {
    unsigned short u = w2raw[i];
    int ex = (u >> 7) & 0xFF;
    if (ex != 0 && (ex < 0x69 || ex > 0x84)) local++;
  }
  atomicAdd(&cnt, local);
  __syncthreads();
  if (threadIdx.x == 0) *flag = (cnt > nelems / 8) ? 1 : 0;
}

// ---- conv1 weight repack: OIHW [64][3][3][3] -> fp32 [27][64] ----
__global__ void fsc_repack_w1_k(const void* __restrict__ W, float* __restrict__ Wr,
                                const int* __restrict__ flag) {
  const int isf32 = *flag;
  int i = blockIdx.x * blockDim.x + threadIdx.x;
  if (i >= 64 * 27) return;
  int co = i / 27;
  int r = i - co * 27;
  Wr[r * 64 + co] = load_ext(W, i, isf32);
}

// ---- MFMA weight repack: OIHW [64][64][3][3] -> bf16 A-fragment order ----
__global__ void fsc_repack_wm_k(const void* __restrict__ W,
                                __hip_bfloat16* __restrict__ Wf,
                                const int* __restrict__ flag) {
  const int isf32 = *flag;
  int o = blockIdx.x * blockDim.x + threadIdx.x;
  if (o >= 36864) return;
  int j = o & 7;
  int lane = (o >> 3) & 63;
  int t = (o >> 9) & 3;
  int kk = o >> 11;       // 0..17
  int s = kk & 1;
  int khw = kk >> 1;      // kh*3+kw
  int kh = khw / 3, kw = khw - kh * 3;
  int co = t * 16 + (lane & 15);
  int ci = s * 32 + (lane >> 4) * 8 + j;
  float v = load_ext(W, (size_t)((co * 64 + ci) * 3 + kh) * 3 + kw, isf32);
  Wf[o] = __float2bfloat16(v);
}

// ---- zero the 1-px border of an NHWC-padded [N][P][P][64] bf16 buffer ----
template <int P>
__global__ void fsc_zero_border_k(__hip_bfloat16* __restrict__ buf, int N) {
  int i = blockIdx.x * blockDim.x + threadIdx.x;
  const int RP = 4 * P - 4;
  if (i >= N * RP * 64) return;
  int c = i & 63;
  int r = (i >> 6) % RP;
  int n = (i >> 6) / RP;
  int row, colp;
  if (r < P) { row = 0; colp = r; }
  else if (r < 2 * P) { row = P - 1; colp = r - P; }
  else if (r < 3 * P - 2) { row = r - 2 * P + 1; colp = 0; }
  else { row = r - (3 * P - 2) + 1; colp = P - 1; }
  buf[(((size_t)n * P + row) * P + colp) * 64 + c] = __float2bfloat16(0.f);
}

// ---- conv1: ext [n][3][84][84] -> bf16 NHWC-padded [n][44][44][64], pad (0,1).
//      2 channel groups (blockIdx.y), acc[32] -> no scratch spill. ----
__global__ void fsc_conv1_k(const void* __restrict__ x, size_t base,
                            const float* __restrict__ Wr, const void* __restrict__ bias,
                            __hip_bfloat16* __restrict__ out, int N,
                            const int* __restrict__ flag) {
  const int isf32 = *flag;
  const int g = blockIdx.y;  // 0..1
  int idx = blockIdx.x * blockDim.x + threadIdx.x;
  const int n = idx / 1764;
  const int sp = idx - n * 1764;
  if (n >= N) return;
  const int ho = sp / 42, wo = sp - ho * 42;
  float acc[32];
#pragma unroll
  for (int j = 0; j < 32; ++j) acc[j] = 0.f;
  const size_t inn = base + (size_t)n * 21168;  // 3*84*84
  const float* wbase = Wr + g * 32;
  for (int ci = 0; ci < 3; ++ci) {
#pragma unroll
    for (int kh = 0; kh < 3; ++kh) {
      const int hi = 2 * ho + kh;
      const bool hok = hi < 84;
#pragma unroll
      for (int kw = 0; kw < 3; ++kw) {
        const int wi = 2 * wo + kw;
        const float val =
            (hok && wi < 84) ? load_ext(x, inn + (ci * 84 + hi) * 84 + wi, isf32) : 0.f;
        const float* wp = wbase + ((ci * 3 + kh) * 3 + kw) * 64;
#pragma unroll
        for (int j = 0; j < 32; ++j) acc[j] = fmaf(wp[j], val, acc[j]);
      }
    }
  }
  __hip_bfloat16* o =
      out + (size_t)n * 123904 + ((size_t)(ho + 1) * 44 + (wo + 1)) * 64 + g * 32;
#pragma unroll
  for (int jj = 0; jj < 16; ++jj) {
    float r0 = acc[2 * jj] + load_ext(bias, g * 32 + 2 * jj, isf32);
    float r1 = acc[2 * jj + 1] + load_ext(bias, g * 32 + 2 * jj + 1, isf32);
    r0 = r0 > 0.f ? r0 : 0.f;
    r1 = r1 > 0.f ? r1 : 0.f;
    union { unsigned short u[2]; unsigned int w; } pk;
    pk.u[0] = __bfloat16_as_ushort(__float2bfloat16(r0));
    pk.u[1] = __bfloat16_as_ushort(__float2bfloat16(r1));
    *(unsigned int*)(void*)(o + 2 * jj) = pk.w;
  }
}

// ---- implicit-GEMM MFMA conv: 64ci -> 64co, 3x3 stride 2.
// Wave = 32 output columns x 64 couts: 2 B-frags share each A-frag.
// in: bf16 NHWC-padded [img][PWI][PWI][64] (zero border), Wf: A-frag weights.
template <int HO, int PWI, int PWO, int ROFF, bool EMB_OUT>
__global__ void fsc_convm_k(const __hip_bfloat16* __restrict__ in,
                            const __hip_bfloat16* __restrict__ Wf,
                            const void* __restrict__ bias, void* __restrict__ out,
                            int N, const int* __restrict__ flag) {
  constexpr int TPI = (HO * HO + 31) / 32;
  const int wid = blockIdx.x * 4 + (threadIdx.x >> 6);
  const int img = wid / TPI;
  if (img >= N) return;
  const int tl = wid - img * TPI;
  const int lane = threadIdx.x & 63;
  const int nidx = lane & 15, quad = lane >> 4;

  int col0 = tl * 32 + nidx;
  int col1 = col0 + 16;
  const bool val0 = col0 < HO * HO;
  const bool val1 = col1 < HO * HO;
  if (!val0) col0 = HO * HO - 1;
  if (!val1) col1 = HO * HO - 1;
  const int ho0 = col0 / HO, wo0 = col0 - ho0 * HO;
  const int ho1 = col1 / HO, wo1 = col1 - ho1 * HO;

  const __hip_bfloat16* bsrc0 =
      in + (((size_t)img * PWI + (2 * ho0 + ROFF)) * PWI + (2 * wo0 + ROFF)) * 64 + quad * 8;
  const __hip_bfloat16* bsrc1 =
      in + (((size_t)img * PWI + (2 * ho1 + ROFF)) * PWI + (2 * wo1 + ROFF)) * 64 + quad * 8;
  const __hip_bfloat16* asrc = Wf + lane * 8;

  f32x4 acc[2][4];
#pragma unroll
  for (int p = 0; p < 2; ++p)
#pragma unroll
    for (int t = 0; t < 4; ++t) acc[p][t] = (f32x4){0.f, 0.f, 0.f, 0.f};

#pragma unroll
  for (int kk = 0; kk < 18; ++kk) {
    const int s = kk & 1;
    const int khw = kk >> 1;
    const int kh = khw / 3, kw = khw - kh * 3;
    const int boff = (kh * PWI + kw) * 64 + s * 32;
    bf16x8 b0 = *(const bf16x8*)(const void*)(bsrc0 + boff);
    bf16x8 b1 = *(const bf16x8*)(const void*)(bsrc1 + boff);
#pragma unroll
    for (int t = 0; t < 4; ++t) {
      bf16x8 a = *(const bf16x8*)(const void*)(asrc + (kk * 4 + t) * 512);
      acc[0][t] = __builtin_amdgcn_mfma_f32_16x16x32_bf16(a, b0, acc[0][t], 0, 0, 0);
      acc[1][t] = __builtin_amdgcn_mfma_f32_16x16x32_bf16(a, b1, acc[1][t], 0, 0, 0);
    }
  }

  const int isf32 = *flag;
#pragma unroll
  for (int p = 0; p < 2; ++p) {
    const bool valid = p == 0 ? val0 : val1;
    const int col = p == 0 ? col0 : col1;
    const int ho = p == 0 ? ho0 : ho1;
    const int wo = p == 0 ? wo0 : wo1;
#pragma unroll
    for (int t = 0; t < 4; ++t) {
      float v[4];
#pragma unroll
      for (int r = 0; r < 4; ++r) {
        const int cout = t * 16 + quad * 4 + r;
        float xv = acc[p][t][r] + load_ext(bias, cout, isf32);
        v[r] = xv > 0.f ? xv : 0.f;
      }
      if (valid) {
        if (EMB_OUT) {
          float* o = (float*)out + ((size_t)img * HO * HO + col) * 64 + t * 16 + quad * 4;
          *(f32x4*)(void*)o = (f32x4){v[0], v[1], v[2], v[3]};
        } else {
          __hip_bfloat16* o = (__hip_bfloat16*)out +
                              (((size_t)img * PWO + (ho + 1)) * PWO + (wo + 1)) * 64 +
                              t * 16 + quad * 4;
          union { unsigned short u[4]; uint2 w; } pk;
#pragma unroll
          for (int r = 0; r < 4; ++r) pk.u[r] = __bfloat16_as_ushort(__float2bfloat16(v[r]));
          *(uint2*)(void*)o = pk.w;
        }
      }
    }
  }
}

// ---- head (proven r3-r5; emb rows NHWC-permuted - head is perm-invariant) ----
__global__ void fsc_proto_k(const float* __restrict__ emb_s, const int* __restrict__ y,
                            float* __restrict__ protos) {
  int i = blockIdx.x * blockDim.x + threadIdx.x;
  if (i >= BB * CC * DD) return;
  int d = i % DD;
  int bc = i / DD;
  int c = bc % CC;
  int b = bc / CC;
  float sum = 0.f;
  for (int s = 0; s < SS; ++s) {
    if (y[b * SS + s] % CC == c) sum += emb_s[(size_t)(b * SS + s) * DD + d];
  }
  protos[i] = sum * 0.2f;
}

__global__ void fsc_pnorm_k(const float* __restrict__ protos, float* __restrict__ pn) {
  __shared__ float red[4];
  __shared__ float inv;
  const int bc = blockIdx.x;
  const float* p = protos + (size_t)bc * DD;
  float ss = 0.f;
  for (int d = threadIdx.x; d < DD; d += 256) { float v = p[d]; ss += v * v; }
#pragma unroll
  for (int off = 32; off > 0; off >>= 1) ss += __shfl_down(ss, off);
  if ((threadIdx.x & 63) == 0) red[threadIdx.x >> 6] = ss;
  __syncthreads();
  if (threadIdx.x == 0) {
    float nrm = sqrtf(red[0] + red[1] + red[2] + red[3]);
    nrm = nrm > EPSF ? nrm : EPSF;
    inv = 1.f / nrm;
  }
  __syncthreads();
  float sc = inv;
  for (int d = threadIdx.x; d < DD; d += 256) pn[(size_t)bc * DD + d] = p[d] * sc;
}

__global__ void fsc_preds_k(const float* __restrict__ emb_t, const float* __restrict__ pn,
                            void* __restrict__ out, const int* __restrict__ flag) {
  __shared__ float red[4][6];
  __shared__ float fin[6];
  const int isf32 = *flag;
  const int bt = blockIdx.x;
  const int b = bt / TT;
  const float* et = emb_t + (size_t)bt * DD;
  float e[9];
#pragma unroll
  for (int k = 0; k < 9; ++k) e[k] = et[threadIdx.x + 256 * k];
  float vals[6];
  {
    float ss = 0.f;
#pragma unroll
    for (int k = 0; k < 9; ++k) ss += e[k] * e[k];
    vals[0] = ss;
  }
  const float* pb = pn + (size_t)b * CC * DD;
#pragma unroll
  for (int c = 0; c < CC; ++c) {
    float s = 0.f;
#pragma unroll
    for (int k = 0; k < 9; ++k) s += e[k] * pb[(size_t)c * DD + threadIdx.x + 256 * k];
    vals[1 + c] = s;
  }
#pragma unroll
  for (int v = 0; v < 6; ++v) {
#pragma unroll
    for (int off = 32; off > 0; off >>= 1) vals[v] += __shfl_down(vals[v], off);
  }
  if ((threadIdx.x & 63) == 0) {
#pragma unroll
    for (int v = 0; v < 6; ++v) red[threadIdx.x >> 6][v] = vals[v];
  }
  __syncthreads();
  if (threadIdx.x < 6)
    fin[threadIdx.x] = red[0][threadIdx.x] + red[1][threadIdx.x] +
                       red[2][threadIdx.x] + red[3][threadIdx.x];
  __syncthreads();
  if (threadIdx.x < CC) {
    float nt = sqrtf(fin[0]);
    nt = nt > EPSF ? nt : EPSF;
    float r = fin[1 + threadIdx.x] / nt;
    if (isf32) ((float*)out)[(size_t)bt * CC + threadIdx.x] = r;
    else ((__hip_bfloat16*)out)[(size_t)bt * CC + threadIdx.x] = __float2bfloat16(r);
  }
}

static inline int fsc_cdiv(int a, int b) { return (a + b - 1) / b; }

extern "C" void kernel_launch(void* const* d_in, const int* in_sizes, int n_in,
                              void* d_out, int out_size, void* d_ws, size_t ws_size,
                              hipStream_t stream) {
  const void* xs = d_in[0];
  const void* xt = d_in[1];
  const int* y = (const int*)d_in[2];
  const void* W1 = d_in[3];
  const void* b1 = d_in[4];
  const void* W2 = d_in[5];
  const void* b2 = d_in[6];
  const void* W3 = d_in[7];
  const void* b3 = d_in[8];
  const void* W4 = d_in[9];
  const void* b4 = d_in[10];

  // ---- workspace layout ----
  char* w = (char*)d_ws;
  int* flag = (int*)w;                     w += 256;
  float* W1r = (float*)w;                  w += 27 * 64 * 4;
  __hip_bfloat16* Wf2 = (__hip_bfloat16*)w; w += 36864 * 2;
  __hip_bfloat16* Wf3 = (__hip_bfloat16*)w; w += 36864 * 2;
  __hip_bfloat16* Wf4 = (__hip_bfloat16*)w; w += 36864 * 2;
  float* protos = (float*)w;               w += (size_t)BB * CC * DD * 4;
  float* pn = (float*)w;                   w += (size_t)BB * CC * DD * 4;
  __hip_bfloat16* c3full = (__hip_bfloat16*)w; w += (size_t)NTOT * 13 * 13 * 64 * 2;
  char* chunk0 = w;
  const size_t fixedB = (size_t)(w - (char*)d_ws);
  const size_t perImgB = ((size_t)44 * 44 * 64 + (size_t)23 * 23 * 64) * 2;

  int CH = 24;  // floor: emb alias needs CH*perImgB >= 800*2304*4
  const int cands[7] = {128, 96, 72, 64, 48, 32, 24};
  for (int k = 0; k < 7; ++k) {
    if (fixedB + (size_t)cands[k] * perImgB <= ws_size) { CH = cands[k]; break; }
  }
  __hip_bfloat16* A1 = (__hip_bfloat16*)chunk0;
  __hip_bfloat16* A2 = (__hip_bfloat16*)(chunk0 + (size_t)CH * 44 * 44 * 64 * 2);
  float* emb = (float*)chunk0;  // phase-2 alias (chunk bufs dead), [800][2304]

  // 1. dtype probe + weight repacks
  fsc_probe_dtype_k<<<1, 256, 0, stream>>>((const unsigned short*)W2, 64 * 64 * 9, flag);
  fsc_repack_w1_k<<<fsc_cdiv(64 * 27, 256), 256, 0, stream>>>(W1, W1r, flag);
  fsc_repack_wm_k<<<fsc_cdiv(36864, 256), 256, 0, stream>>>(W2, Wf2, flag);
  fsc_repack_wm_k<<<fsc_cdiv(36864, 256), 256, 0, stream>>>(W3, Wf3, flag);
  fsc_repack_wm_k<<<fsc_cdiv(36864, 256), 256, 0, stream>>>(W4, Wf4, flag);

  // 2. zero NHWC borders (interiors fully overwritten by convs)
  fsc_zero_border_k<44><<<fsc_cdiv(CH * (4 * 44 - 4) * 64, 256), 256, 0, stream>>>(A1, CH);
  fsc_zero_border_k<23><<<fsc_cdiv(CH * (4 * 23 - 4) * 64, 256), 256, 0, stream>>>(A2, CH);
  fsc_zero_border_k<13><<<fsc_cdiv(NTOT * (4 * 13 - 4) * 64, 256), 256, 0, stream>>>(c3full, NTOT);

  // 3. conv1 (VALU, 2 grp) -> conv2 (MFMA) -> conv3 (MFMA, full-batch out), chunked
  auto run_set = [&](const void* x, int count, int gbase) {
    for (int off = 0; off < count; off += CH) {
      const int n = (count - off) < CH ? (count - off) : CH;
      fsc_conv1_k<<<dim3(fsc_cdiv(n * 1764, 256), 2), 256, 0, stream>>>(
          x, (size_t)off * 21168, W1r, b1, A1, n, flag);
      // conv2: 44-pad -> 21x21 into 23-pad; ROFF=1; TPI=14
      fsc_convm_k<21, 44, 23, 1, false><<<fsc_cdiv(n * 14, 4), 256, 0, stream>>>(
          A1, Wf2, b2, A2, n, flag);
      // conv3: 23-pad -> 11x11 into 13-pad; ROFF=0; TPI=4
      fsc_convm_k<11, 23, 13, 0, false><<<fsc_cdiv(n * 4, 4), 256, 0, stream>>>(
          A2, Wf3, b3, c3full + (size_t)(gbase + off) * 13 * 13 * 64, n, flag);
    }
  };
  run_set(xs, NSUP, 0);
  run_set(xt, NTGT, NSUP);

  // 4. conv4 full batch (MFMA): 13-pad -> fp32 emb [800][2304]; TPI=2
  fsc_convm_k<6, 13, 0, 0, true><<<fsc_cdiv(NTOT * 2, 4), 256, 0, stream>>>(
      c3full, Wf4, b4, emb, NTOT, flag);

  // 5. head
  fsc_proto_k<<<fsc_cdiv(BB * CC * DD, 256), 256, 0, stream>>>(emb, y, protos);
  fsc_pnorm_k<<<BB * CC, 256, 0, stream>>>(protos, pn);
  fsc_preds_k<<<NTGT, 256, 0, stream>>>(emb + (size_t)NSUP * DD, pn, d_out, flag);
}